// Round 1
// baseline (5602.164 us; speedup 1.0000x reference)
//
// Persistent cooperative LSTM kernel for MI355X (gfx950).
// Design notes (round 0):
//  - 256 blocks x 256 threads, 1 block/CU. Block b owns hidden units 4b..4b+3
//    of BOTH layers (16 gate rows: cols = gate*4+u, gate in {i,f,g,o}).
//  - All recurrent weights converted to bf16 MFMA B-fragments held in VGPRs:
//    whh0f/wih1f/whh1f/wfusedf/wfcf, 8 k-steps each (K split across 4 waves).
//  - Decode feedback folded: Wfused = Wih0@W2 (pred->x path), Wskip/u-state
//    (lp path). pred computed only once at the end (output GEMM phase).
//  - Grid barrier: monotonic 16x16 counter tree in ws + threadfence.
//  - ws layout: [0,8K) barrier, [8K,..) h0[2],h1[2] bf16, [520K..) relu[32] bf16.
#include <hip/hip_runtime.h>

typedef __attribute__((ext_vector_type(8))) short short8;
typedef __attribute__((ext_vector_type(4))) float float4_;

#define AGENT __HIP_MEMORY_SCOPE_AGENT

__device__ __forceinline__ unsigned short f2bf(float f) {
    unsigned u = __builtin_bit_cast(unsigned, f);
    u = (u + 0x7FFFu + ((u >> 16) & 1u)) >> 16;
    return (unsigned short)u;
}
__device__ __forceinline__ float bf2f(unsigned short h) {
    unsigned u = ((unsigned)h) << 16;
    return __builtin_bit_cast(float, u);
}
__device__ __forceinline__ float sigm(float x) { return 1.0f / (1.0f + __expf(-x)); }
__device__ __forceinline__ float tanhf_(float x) {
    x = fminf(fmaxf(x, -15.0f), 15.0f);
    float e = __expf(2.0f * x);
    return (e - 1.0f) / (e + 1.0f);
}

// ---- grid barrier: 16 groups of 16 blocks, monotonic counters ----
__device__ __forceinline__ void gbar(unsigned* bar, unsigned target, int grpId) {
    __syncthreads();
    if (threadIdx.x == 0) {
        __threadfence();
        unsigned old = __hip_atomic_fetch_add(bar + grpId * 64, 1u, __ATOMIC_RELAXED, AGENT);
        if ((old & 15u) == 15u) {
            unsigned old2 = __hip_atomic_fetch_add(bar + 1024, 1u, __ATOMIC_RELAXED, AGENT);
            if ((old2 & 15u) == 15u) {
                __threadfence();
                __hip_atomic_store(bar + 1088, target, __ATOMIC_RELEASE, AGENT);
            }
        }
        while (__hip_atomic_load(bar + 1088, __ATOMIC_RELAXED, AGENT) < target)
            __builtin_amdgcn_s_sleep(2);
        __threadfence();
    }
    __syncthreads();
}

__device__ __forceinline__ void zero4(float4_ (&a)[4]) {
    float4_ z;
    z[0] = 0.f; z[1] = 0.f; z[2] = 0.f; z[3] = 0.f;
#pragma unroll
    for (int i = 0; i < 4; i++) a[i] = z;
}

// A[m][k]: m = lane&15 (batch row in 16-tile), k = quad*8+j (contiguous 8 bf16)
// B[k][n]: n = lane&15 (gate col),             k = quad*8+j
// C[m][n]: n = lane&15, m = quad*4+reg
__device__ __forceinline__ void mm_pass(const unsigned short* __restrict__ A,
                                        int q, int lane,
                                        const short8 (&bf)[8], float4_ (&acc)[4]) {
    const int r0 = lane & 15;
    const int kq = (q << 8) + ((lane >> 4) << 3);
#pragma unroll
    for (int mt = 0; mt < 4; mt++) {
        const unsigned short* Ar = A + (mt * 16 + r0) * 1024 + kq;
#pragma unroll
        for (int s = 0; s < 8; s++) {
            short8 a = *(const short8*)(Ar + s * 32);
            acc[mt] = __builtin_amdgcn_mfma_f32_16x16x32_bf16(a, bf[s], acc[mt], 0, 0, 0);
        }
    }
}

__device__ __forceinline__ void write_parts(float* gp, int q, int lane, float4_ (&acc)[4]) {
    const int col = lane & 15;
    const int rbase = (lane >> 4) * 4;
#pragma unroll
    for (int mt = 0; mt < 4; mt++)
#pragma unroll
        for (int r = 0; r < 4; r++)
            gp[(q * 64 + mt * 16 + rbase + r) * 17 + col] = acc[mt][r];
}

__device__ __forceinline__ float gsum(const float* gp, int b, int c) {
    return gp[(0 * 64 + b) * 17 + c] + gp[(1 * 64 + b) * 17 + c] +
           gp[(2 * 64 + b) * 17 + c] + gp[(3 * 64 + b) * 17 + c];
}

__device__ __forceinline__ short8 packrow(const float* __restrict__ p) {
    short8 r;
#pragma unroll
    for (int j = 0; j < 8; j++) r[j] = (short)f2bf(p[j]);
    return r;
}

__global__ void __launch_bounds__(256, 1)
lstm_core(const float* __restrict__ x, const float* __restrict__ lastp,
          const float* __restrict__ Wih0, const float* __restrict__ Whh0,
          const float* __restrict__ bih0, const float* __restrict__ bhh0,
          const float* __restrict__ Wih1, const float* __restrict__ Whh1,
          const float* __restrict__ bih1, const float* __restrict__ bhh1,
          const float* __restrict__ W1, const float* __restrict__ b1,
          const float* __restrict__ W2, const float* __restrict__ b2,
          float* __restrict__ out, unsigned char* __restrict__ wsb)
{
    const int tid = threadIdx.x;
    const int blk = blockIdx.x;
    const int lane = tid & 63;
    const int q = tid >> 6;          // wave id = K quarter
    const int grpId = blk & 15;
    const int b_ = tid & 63;         // batch row this thread owns in epilogues
    const int u_ = tid >> 6;         // unit-within-block (0..3)
    const int D_ = blk * 4 + u_;     // global hidden unit / fc dim

    unsigned* bar = (unsigned*)wsb;
    unsigned short* h0buf[2] = {(unsigned short*)(wsb + 8192),
                                (unsigned short*)(wsb + 8192 + 131072)};
    unsigned short* h1buf[2] = {(unsigned short*)(wsb + 270336),
                                (unsigned short*)(wsb + 270336 + 131072)};
    unsigned short* relub = (unsigned short*)(wsb + 532480); // 32 slots x 65536 ushort

    __shared__ float gparts[4 * 64 * 17];
    __shared__ float xlds[64 * 21];
    __shared__ float wih0l[16 * 20];

    // ---- barrier area init (block 0) ----
    if (blk == 0 && tid == 0) {
        for (int i = 0; i < 16; i++)
            __hip_atomic_store(bar + i * 64, 0u, __ATOMIC_RELAXED, AGENT);
        __hip_atomic_store(bar + 1024, 0u, __ATOMIC_RELAXED, AGENT);
        __hip_atomic_store(bar + 1088, 0u, __ATOMIC_RELAXED, AGENT);
        __threadfence();
        __hip_atomic_store(bar + 1152, 0x1357BDFu, __ATOMIC_RELEASE, AGENT);
    }

    // ---- per-lane B-fragment preload (bf16, RNE) ----
    const int n_ = lane & 15;
    const int gq_ = n_ >> 2, uu_ = n_ & 3;
    const int growL = gq_ * 1024 + blk * 4 + uu_;   // gate row for this col
    const int kq = (q << 8) + ((lane >> 4) << 3);

    short8 whh0f[8], wih1f[8], whh1f[8], wfusedf[8], wfcf[8];
#pragma unroll
    for (int s = 0; s < 8; s++) {
        const int k = kq + s * 32;
        whh0f[s] = packrow(Whh0 + growL * 1024 + k);
        wih1f[s] = packrow(Wih1 + growL * 1024 + k);
        whh1f[s] = packrow(Whh1 + growL * 1024 + k);
        { // Wfused[row][k] = sum_m Wih0[row][m] * W2[m][k]
            float a8[8] = {0.f, 0.f, 0.f, 0.f, 0.f, 0.f, 0.f, 0.f};
            for (int m = 0; m < 20; m++) {
                float wv = Wih0[growL * 20 + m];
                const float* w2p = W2 + m * 1024 + k;
#pragma unroll
                for (int j = 0; j < 8; j++) a8[j] += wv * w2p[j];
            }
            short8 r;
#pragma unroll
            for (int j = 0; j < 8; j++) r[j] = (short)f2bf(a8[j]);
            wfusedf[s] = r;
        }
        { // fc B: cols 0-3 = W1h rows, cols 4-7 = Wskip rows, 8-15 = 0
            short8 r;
            if (n_ < 4) {
                r = packrow(W1 + (blk * 4 + n_) * 1040 + k);
            } else if (n_ < 8) {
                const int D = blk * 4 + (n_ - 4);
                float a8[8] = {0.f, 0.f, 0.f, 0.f, 0.f, 0.f, 0.f, 0.f};
                for (int g2 = 0; g2 < 16; g2++) {
                    const int m = 5 * (g2 >> 2) + (g2 & 3);
                    float wv = W1[D * 1040 + 1024 + g2] * 0.01f;
                    const float* w2p = W2 + m * 1024 + k;
#pragma unroll
                    for (int j = 0; j < 8; j++) a8[j] += wv * w2p[j];
                }
#pragma unroll
                for (int j = 0; j < 8; j++) r[j] = (short)f2bf(a8[j]);
            } else {
#pragma unroll
                for (int j = 0; j < 8; j++) r[j] = 0;
            }
            wfcf[s] = r;
        }
    }

    // ---- per-thread constants ----
    float bias0g[4], bias1g[4], cgv[4];
#pragma unroll
    for (int g = 0; g < 4; g++) {
        const int row = g * 1024 + D_;
        bias0g[g] = bih0[row] + bhh0[row];
        bias1g[g] = bih1[row] + bhh1[row];
        float s = 0.f;
        for (int m = 0; m < 20; m++) s += Wih0[row * 20 + m] * b2[m];
        cgv[g] = s;
    }
    const float fcb = b1[D_];
    float cbv = 0.f, ustate = 0.f;
    for (int g2 = 0; g2 < 16; g2++) {
        const float w1v = W1[D_ * 1040 + 1024 + g2];
        cbv += b2[5 * (g2 >> 2) + (g2 & 3)] * w1v * 0.01f;
        ustate += lastp[b_ * 16 + g2] * w1v;   // u(0) = lp0 @ W1lp^T
    }
    float c0v = 0.f, c1v = 0.f;

    if (tid < 16) { // Wih0 rows for x-path (fp32, exact)
        const int row = (tid >> 2) * 1024 + blk * 4 + (tid & 3);
        for (int m = 0; m < 20; m++) wih0l[tid * 20 + m] = Wih0[row * 20 + m];
    }
    // zero initial h state (parity 1 is "t = -1")
    h0buf[1][b_ * 1024 + D_] = 0;
    h1buf[1][b_ * 1024 + D_] = 0;

    if (tid == 0) {
        while (__hip_atomic_load(bar + 1152, __ATOMIC_RELAXED, AGENT) != 0x1357BDFu)
            __builtin_amdgcn_s_sleep(2);
    }
    unsigned tgt = 1;
    gbar(bar, tgt++, grpId);

    // ---- phase lambdas ----
    auto do_l0 = [&](const unsigned short* h0prev, unsigned short* h0dst,
                     const unsigned short* reluprev, int xt) {
        float4_ acc[4];
        zero4(acc);
        mm_pass(h0prev, q, lane, whh0f, acc);
        if (reluprev) mm_pass(reluprev, q, lane, wfusedf, acc);
        if (xt >= 0) {
            for (int i = tid; i < 1280; i += 256) {
                const int bb = i / 20, mm = i - bb * 20;
                xlds[bb * 21 + mm] = x[bb * 1280 + xt * 20 + mm];
            }
        }
        write_parts(gparts, q, lane, acc);
        __syncthreads();
        float gv[4];
#pragma unroll
        for (int g = 0; g < 4; g++) gv[g] = gsum(gparts, b_, g * 4 + u_) + bias0g[g];
        if (xt >= 0) {
#pragma unroll
            for (int g = 0; g < 4; g++) {
                float s = 0.f;
                const float* wr = &wih0l[(g * 4 + u_) * 20];
                const float* xr = &xlds[b_ * 21];
                for (int m = 0; m < 20; m++) s += xr[m] * wr[m];
                gv[g] += s;
            }
        } else {
#pragma unroll
            for (int g = 0; g < 4; g++) gv[g] += cgv[g];
        }
        const float iv = sigm(gv[0]), fv = sigm(gv[1]);
        const float gt = tanhf_(gv[2]), ov = sigm(gv[3]);
        c0v = fv * c0v + iv * gt;
        h0dst[b_ * 1024 + D_] = (unsigned short)f2bf(ov * tanhf_(c0v));
    };

    auto do_l1 = [&](const unsigned short* h0cur, const unsigned short* h1prev,
                     unsigned short* h1dst) {
        float4_ acc[4];
        zero4(acc);
        mm_pass(h0cur, q, lane, wih1f, acc);
        mm_pass(h1prev, q, lane, whh1f, acc);
        write_parts(gparts, q, lane, acc);
        __syncthreads();
        float gv[4];
#pragma unroll
        for (int g = 0; g < 4; g++) gv[g] = gsum(gparts, b_, g * 4 + u_) + bias1g[g];
        const float iv = sigm(gv[0]), fv = sigm(gv[1]);
        const float gt = tanhf_(gv[2]), ov = sigm(gv[3]);
        c1v = fv * c1v + iv * gt;
        h1dst[b_ * 1024 + D_] = (unsigned short)f2bf(ov * tanhf_(c1v));
    };

    auto do_fc = [&](int t, const unsigned short* h1cur, const unsigned short* reluprev) {
        float4_ acc1[4], acc2[4];
        zero4(acc1);
        zero4(acc2);
        mm_pass(h1cur, q, lane, wfcf, acc1);              // cols 0-3 valid: W1h@h1
        if (reluprev) mm_pass(reluprev, q, lane, wfcf, acc2); // cols 4-7 valid: Wskip@relu
        {
            const int col = lane & 15;
            const int rbase = (lane >> 4) * 4;
            if (col < 8) {
#pragma unroll
                for (int mt = 0; mt < 4; mt++)
#pragma unroll
                    for (int r = 0; r < 4; r++) {
                        const float v = (col < 4) ? acc1[mt][r] : acc2[mt][r];
                        gparts[(q * 64 + mt * 16 + rbase + r) * 17 + col] = v;
                    }
            }
        }
        __syncthreads();
        const float s1 = gsum(gparts, b_, u_);
        if (t > 0) ustate += gsum(gparts, b_, 4 + u_) + cbv;
        const float rv = fmaxf(s1 + ustate + fcb, 0.f);
        relub[t * 65536 + b_ * 1024 + D_] = (unsigned short)f2bf(rv);
    };

    // ---- encoder: 64 steps x {L0, L1} ----
    for (int t = 0; t < 64; t++) {
        unsigned short* h0c = h0buf[t & 1];
        unsigned short* h0p = h0buf[(t + 1) & 1];
        unsigned short* h1c = h1buf[t & 1];
        unsigned short* h1p = h1buf[(t + 1) & 1];
        do_l0(h0p, h0c, nullptr, t);
        gbar(bar, tgt++, grpId);
        do_l1(h0c, h1p, h1c);
        gbar(bar, tgt++, grpId);
    }
    // ---- decoder: 32 steps x {L0, L1, FC} ----
    for (int t = 0; t < 32; t++) {
        unsigned short* h0c = h0buf[t & 1];
        unsigned short* h0p = h0buf[(t + 1) & 1];
        unsigned short* h1c = h1buf[t & 1];
        unsigned short* h1p = h1buf[(t + 1) & 1];
        const unsigned short* rp = (t > 0) ? (relub + (t - 1) * 65536) : nullptr;
        do_l0(h0p, h0c, rp, (t == 0) ? 63 : -1);
        gbar(bar, tgt++, grpId);
        do_l1(h0c, h1p, h1c);
        gbar(bar, tgt++, grpId);
        do_fc(t, h1c, rp);
        gbar(bar, tgt++, grpId);
    }

    // ---- final: pred[t] = relu[t] @ W2^T + b2 -> out[b][t][m] ----
    {
        const int pj = tid >> 5;   // 8 (t,b) pairs per block
        const int m = tid & 31;
        if (m < 20) {
            const int pidx = blk * 8 + pj;
            const int tt = pidx >> 6, bb = pidx & 63;
            const unsigned short* rr = relub + tt * 65536 + bb * 1024;
            const float* w = W2 + m * 1024;
            float acc = 0.f;
            for (int k2 = 0; k2 < 1024; k2 += 8) {
                short8 r8 = *(const short8*)(rr + k2);
#pragma unroll
                for (int j = 0; j < 8; j++)
                    acc += bf2f((unsigned short)r8[j]) * w[k2 + j];
            }
            out[bb * 640 + tt * 20 + m] = acc + b2[m];
        }
    }
}

extern "C" void kernel_launch(void* const* d_in, const int* in_sizes, int n_in,
                              void* d_out, int out_size, void* d_ws, size_t ws_size,
                              hipStream_t stream) {
    (void)in_sizes; (void)n_in; (void)out_size; (void)ws_size;
    const float* x     = (const float*)d_in[0];
    const float* lastp = (const float*)d_in[1];
    const float* Wih0  = (const float*)d_in[2];
    const float* Whh0  = (const float*)d_in[3];
    const float* bih0  = (const float*)d_in[4];
    const float* bhh0  = (const float*)d_in[5];
    const float* Wih1  = (const float*)d_in[6];
    const float* Whh1  = (const float*)d_in[7];
    const float* bih1  = (const float*)d_in[8];
    const float* bhh1  = (const float*)d_in[9];
    const float* W1    = (const float*)d_in[10];
    const float* b1    = (const float*)d_in[11];
    const float* W2    = (const float*)d_in[12];
    const float* b2    = (const float*)d_in[13];
    float* out = (float*)d_out;
    unsigned char* ws = (unsigned char*)d_ws;

    void* args[] = {&x, &lastp, &Wih0, &Whh0, &bih0, &bhh0, &Wih1, &Whh1,
                    &bih1, &bhh1, &W1, &b1, &W2, &b2, &out, &ws};
    hipError_t err = hipLaunchCooperativeKernel((const void*)lstm_core,
                                                dim3(256), dim3(256), args, 0, stream);
    if (err != hipSuccess) {
        // fallback: plain launch (256 blocks of 256 thr / 24KB LDS are trivially
        // co-resident on 256 CUs, so the custom barrier still rendezvous)
        hipLaunchKernelGGL(lstm_core, dim3(256), dim3(256), 0, stream,
                           x, lastp, Wih0, Whh0, bih0, bhh0, Wih1, Whh1,
                           bih1, bhh1, W1, b1, W2, b2, out, ws);
    }
}

// Round 2
// 4035.681 us; speedup vs baseline: 1.3882x; 1.3882x over previous
//
// Persistent cooperative LSTM kernel for MI355X (gfx950) — round 2.
//  - 256 blocks x 256 threads, 1 block/CU. Block b owns hidden units 4b..4b+3
//    of BOTH layers. Weights live in VGPRs as bf16 MFMA B-fragments.
//  - R2 changes vs R1 (which was barrier-convoy bound at 24us/phase):
//    (a) distributed-flag barrier: 16 release flags on 16 cachelines,
//        16 pollers each (was: 256 pollers on ONE line -> TCC convoy).
//    (b) blocked h/relu layout hblk[D>>2][b][D&3]: block stores one
//        contiguous 512B (full lines; was 64 RMW partial lines/block/phase
//        -> WRITE_SIZE 618MB).
//    (c) encoder post-L1 barrier elided (proof: L0(t+1) writes h0buf[(t+1)&1],
//        disjoint from L1(t)'s reads h0buf[t&1]/h1buf[(t+1)&1]; post-L0
//        barrier transitively orders L1(t) before L1(t+1)). 225 -> 161 barriers.
#include <hip/hip_runtime.h>

typedef __attribute__((ext_vector_type(8))) short short8;
typedef __attribute__((ext_vector_type(4))) short short4_;
typedef __attribute__((ext_vector_type(4))) float float4_;

#define AGENT __HIP_MEMORY_SCOPE_AGENT

__device__ __forceinline__ unsigned short f2bf(float f) {
    unsigned u = __builtin_bit_cast(unsigned, f);
    u = (u + 0x7FFFu + ((u >> 16) & 1u)) >> 16;
    return (unsigned short)u;
}
__device__ __forceinline__ float bf2f(unsigned short h) {
    unsigned u = ((unsigned)h) << 16;
    return __builtin_bit_cast(float, u);
}
__device__ __forceinline__ float sigm(float x) { return 1.0f / (1.0f + __expf(-x)); }
__device__ __forceinline__ float tanhf_(float x) {
    x = fminf(fmaxf(x, -15.0f), 15.0f);
    float e = __expf(2.0f * x);
    return (e - 1.0f) / (e + 1.0f);
}

// ---- grid barrier ----
// bar layout (uint index): flag[g] at g*16 (g=0..15, one 64B line each),
// arrival[g] at 256+g*16, central at 512, magic at 544.
__device__ __forceinline__ void gbar(unsigned* bar, unsigned target, int grpId) {
    __syncthreads();
    if (threadIdx.x == 0) {
        __threadfence();
        unsigned old = __hip_atomic_fetch_add(bar + 256 + grpId * 16, 1u, __ATOMIC_RELAXED, AGENT);
        if ((old & 15u) == 15u) {
            unsigned old2 = __hip_atomic_fetch_add(bar + 512, 1u, __ATOMIC_RELAXED, AGENT);
            if ((old2 & 15u) == 15u) {
                __threadfence();
#pragma unroll
                for (int g = 0; g < 16; g++)
                    __hip_atomic_store(bar + g * 16, target, __ATOMIC_RELAXED, AGENT);
            }
        }
        while (__hip_atomic_load(bar + grpId * 16, __ATOMIC_RELAXED, AGENT) < target)
            __builtin_amdgcn_s_sleep(2);
        __threadfence();
    }
    __syncthreads();
}

__device__ __forceinline__ void zero4(float4_ (&a)[4]) {
    float4_ z;
    z[0] = 0.f; z[1] = 0.f; z[2] = 0.f; z[3] = 0.f;
#pragma unroll
    for (int i = 0; i < 4; i++) a[i] = z;
}

// A is in blocked layout: element (batch m, unit k) at A[(k>>2)*256 + m*4 + (k&3)].
// A-frag: m = lane&15 (+16*mt), k = quad*8+j. B[k][n]: n = lane&15, k = quad*8+j.
// C[m][n]: n = lane&15, m = quad*4+reg.
__device__ __forceinline__ void mm_pass(const unsigned short* __restrict__ A,
                                        int q, int lane,
                                        const short8 (&bf)[8], float4_ (&acc)[4]) {
    const int r0 = lane & 15;
    const int kq = (q << 8) + ((lane >> 4) << 3);
#pragma unroll
    for (int mt = 0; mt < 4; mt++) {
        const int r4 = (mt * 16 + r0) * 4;
#pragma unroll
        for (int s = 0; s < 8; s++) {
            const unsigned short* p = A + ((kq + s * 32) >> 2) * 256 + r4;
            short4_ lo = *(const short4_*)(p);
            short4_ hi = *(const short4_*)(p + 256);
            short8 a;
#pragma unroll
            for (int j = 0; j < 4; j++) { a[j] = lo[j]; a[j + 4] = hi[j]; }
            acc[mt] = __builtin_amdgcn_mfma_f32_16x16x32_bf16(a, bf[s], acc[mt], 0, 0, 0);
        }
    }
}

__device__ __forceinline__ void write_parts(float* gp, int q, int lane, float4_ (&acc)[4]) {
    const int col = lane & 15;
    const int rbase = (lane >> 4) * 4;
#pragma unroll
    for (int mt = 0; mt < 4; mt++)
#pragma unroll
        for (int r = 0; r < 4; r++)
            gp[(q * 64 + mt * 16 + rbase + r) * 17 + col] = acc[mt][r];
}

__device__ __forceinline__ float gsum(const float* gp, int b, int c) {
    return gp[(0 * 64 + b) * 17 + c] + gp[(1 * 64 + b) * 17 + c] +
           gp[(2 * 64 + b) * 17 + c] + gp[(3 * 64 + b) * 17 + c];
}

__device__ __forceinline__ short8 packrow(const float* __restrict__ p) {
    short8 r;
#pragma unroll
    for (int j = 0; j < 8; j++) r[j] = (short)f2bf(p[j]);
    return r;
}

__global__ void __launch_bounds__(256, 1)
lstm_core(const float* __restrict__ x, const float* __restrict__ lastp,
          const float* __restrict__ Wih0, const float* __restrict__ Whh0,
          const float* __restrict__ bih0, const float* __restrict__ bhh0,
          const float* __restrict__ Wih1, const float* __restrict__ Whh1,
          const float* __restrict__ bih1, const float* __restrict__ bhh1,
          const float* __restrict__ W1, const float* __restrict__ b1,
          const float* __restrict__ W2, const float* __restrict__ b2,
          float* __restrict__ out, unsigned char* __restrict__ wsb)
{
    const int tid = threadIdx.x;
    const int blk = blockIdx.x;
    const int lane = tid & 63;
    const int q = tid >> 6;          // wave id = K quarter
    const int grpId = blk & 15;      // round-robin XCD map keeps a group on-XCD
    const int eb = tid >> 2;         // epilogue: batch row
    const int eu = tid & 3;          // epilogue: unit-within-block
    const int D_ = blk * 4 + eu;     // global hidden unit / fc dim

    unsigned* bar = (unsigned*)wsb;
    unsigned short* h0buf[2] = {(unsigned short*)(wsb + 8192),
                                (unsigned short*)(wsb + 8192 + 131072)};
    unsigned short* h1buf[2] = {(unsigned short*)(wsb + 270336),
                                (unsigned short*)(wsb + 270336 + 131072)};
    unsigned short* relub = (unsigned short*)(wsb + 532480); // 32 x 65536 ushort

    __shared__ float gparts[4 * 64 * 17];
    __shared__ float xlds[64 * 21];
    __shared__ float wih0l[16 * 20];

    // ---- barrier area init (block 0) ----
    if (blk == 0 && tid == 0) {
        for (int g = 0; g < 16; g++) {
            __hip_atomic_store(bar + g * 16, 0u, __ATOMIC_RELAXED, AGENT);
            __hip_atomic_store(bar + 256 + g * 16, 0u, __ATOMIC_RELAXED, AGENT);
        }
        __hip_atomic_store(bar + 512, 0u, __ATOMIC_RELAXED, AGENT);
        __threadfence();
        __hip_atomic_store(bar + 544, 0x1357BDFu, __ATOMIC_RELEASE, AGENT);
    }

    // ---- per-lane B-fragment preload (bf16, RNE) ----
    const int n_ = lane & 15;
    const int gq_ = n_ >> 2, uu_ = n_ & 3;
    const int growL = gq_ * 1024 + blk * 4 + uu_;   // gate row for this col
    const int kq = (q << 8) + ((lane >> 4) << 3);

    short8 whh0f[8], wih1f[8], whh1f[8], wfusedf[8], wfcf[8];
#pragma unroll
    for (int s = 0; s < 8; s++) {
        const int k = kq + s * 32;
        whh0f[s] = packrow(Whh0 + growL * 1024 + k);
        wih1f[s] = packrow(Wih1 + growL * 1024 + k);
        whh1f[s] = packrow(Whh1 + growL * 1024 + k);
        { // Wfused[row][k] = sum_m Wih0[row][m] * W2[m][k]
            float a8[8] = {0.f, 0.f, 0.f, 0.f, 0.f, 0.f, 0.f, 0.f};
            for (int m = 0; m < 20; m++) {
                float wv = Wih0[growL * 20 + m];
                const float* w2p = W2 + m * 1024 + k;
#pragma unroll
                for (int j = 0; j < 8; j++) a8[j] += wv * w2p[j];
            }
            short8 r;
#pragma unroll
            for (int j = 0; j < 8; j++) r[j] = (short)f2bf(a8[j]);
            wfusedf[s] = r;
        }
        { // fc B: cols 0-3 = W1h rows, cols 4-7 = Wskip rows, 8-15 = 0
            short8 r;
            if (n_ < 4) {
                r = packrow(W1 + (blk * 4 + n_) * 1040 + k);
            } else if (n_ < 8) {
                const int D = blk * 4 + (n_ - 4);
                float a8[8] = {0.f, 0.f, 0.f, 0.f, 0.f, 0.f, 0.f, 0.f};
                for (int g2 = 0; g2 < 16; g2++) {
                    const int m = 5 * (g2 >> 2) + (g2 & 3);
                    float wv = W1[D * 1040 + 1024 + g2] * 0.01f;
                    const float* w2p = W2 + m * 1024 + k;
#pragma unroll
                    for (int j = 0; j < 8; j++) a8[j] += wv * w2p[j];
                }
#pragma unroll
                for (int j = 0; j < 8; j++) r[j] = (short)f2bf(a8[j]);
            } else {
#pragma unroll
                for (int j = 0; j < 8; j++) r[j] = 0;
            }
            wfcf[s] = r;
        }
    }

    // ---- per-thread constants (epilogue mapping: eb = tid>>2, eu = tid&3) ----
    float bias0g[4], bias1g[4], cgv[4];
#pragma unroll
    for (int g = 0; g < 4; g++) {
        const int row = g * 1024 + D_;
        bias0g[g] = bih0[row] + bhh0[row];
        bias1g[g] = bih1[row] + bhh1[row];
        float s = 0.f;
        for (int m = 0; m < 20; m++) s += Wih0[row * 20 + m] * b2[m];
        cgv[g] = s;
    }
    const float fcb = b1[D_];
    float cbv = 0.f, ustate = 0.f;
    for (int g2 = 0; g2 < 16; g2++) {
        const float w1v = W1[D_ * 1040 + 1024 + g2];
        cbv += b2[5 * (g2 >> 2) + (g2 & 3)] * w1v * 0.01f;
        ustate += lastp[eb * 16 + g2] * w1v;   // u(0) = lp0 @ W1lp^T
    }
    float c0v = 0.f, c1v = 0.f;

    if (tid < 16) { // Wih0 rows for x-path (fp32, exact)
        const int row = (tid >> 2) * 1024 + blk * 4 + (tid & 3);
        for (int m = 0; m < 20; m++) wih0l[tid * 20 + m] = Wih0[row * 20 + m];
    }
    // zero initial h state (parity 1 is "t = -1"); blocked layout, own slice
    h0buf[1][blk * 256 + tid] = 0;
    h1buf[1][blk * 256 + tid] = 0;

    if (tid == 0) {
        while (__hip_atomic_load(bar + 544, __ATOMIC_RELAXED, AGENT) != 0x1357BDFu)
            __builtin_amdgcn_s_sleep(2);
    }
    unsigned tgt = 1;
    gbar(bar, tgt++, grpId);

    // ---- phase lambdas ----
    auto do_l0 = [&](const unsigned short* h0prev, unsigned short* h0dst,
                     const unsigned short* reluprev, int xt) {
        float4_ acc[4];
        zero4(acc);
        mm_pass(h0prev, q, lane, whh0f, acc);
        if (reluprev) mm_pass(reluprev, q, lane, wfusedf, acc);
        if (xt >= 0) {
            for (int i = tid; i < 1280; i += 256) {
                const int bb = i / 20, mm = i - bb * 20;
                xlds[bb * 21 + mm] = x[bb * 1280 + xt * 20 + mm];
            }
        }
        write_parts(gparts, q, lane, acc);
        __syncthreads();
        float gv[4];
#pragma unroll
        for (int g = 0; g < 4; g++) gv[g] = gsum(gparts, eb, g * 4 + eu) + bias0g[g];
        if (xt >= 0) {
#pragma unroll
            for (int g = 0; g < 4; g++) {
                float s = 0.f;
                const float* wr = &wih0l[(g * 4 + eu) * 20];
                const float* xr = &xlds[eb * 21];
                for (int m = 0; m < 20; m++) s += xr[m] * wr[m];
                gv[g] += s;
            }
        } else {
#pragma unroll
            for (int g = 0; g < 4; g++) gv[g] += cgv[g];
        }
        const float iv = sigm(gv[0]), fv = sigm(gv[1]);
        const float gt = tanhf_(gv[2]), ov = sigm(gv[3]);
        c0v = fv * c0v + iv * gt;
        h0dst[blk * 256 + tid] = (unsigned short)f2bf(ov * tanhf_(c0v));  // coalesced full lines
    };

    auto do_l1 = [&](const unsigned short* h0cur, const unsigned short* h1prev,
                     unsigned short* h1dst) {
        float4_ acc[4];
        zero4(acc);
        mm_pass(h0cur, q, lane, wih1f, acc);
        mm_pass(h1prev, q, lane, whh1f, acc);
        write_parts(gparts, q, lane, acc);
        __syncthreads();
        float gv[4];
#pragma unroll
        for (int g = 0; g < 4; g++) gv[g] = gsum(gparts, eb, g * 4 + eu) + bias1g[g];
        const float iv = sigm(gv[0]), fv = sigm(gv[1]);
        const float gt = tanhf_(gv[2]), ov = sigm(gv[3]);
        c1v = fv * c1v + iv * gt;
        h1dst[blk * 256 + tid] = (unsigned short)f2bf(ov * tanhf_(c1v));
    };

    auto do_fc = [&](int t, const unsigned short* h1cur, const unsigned short* reluprev) {
        float4_ acc1[4], acc2[4];
        zero4(acc1);
        zero4(acc2);
        mm_pass(h1cur, q, lane, wfcf, acc1);              // cols 0-3 valid: W1h@h1
        if (reluprev) mm_pass(reluprev, q, lane, wfcf, acc2); // cols 4-7 valid: Wskip@relu
        {
            const int col = lane & 15;
            const int rbase = (lane >> 4) * 4;
            if (col < 8) {
#pragma unroll
                for (int mt = 0; mt < 4; mt++)
#pragma unroll
                    for (int r = 0; r < 4; r++) {
                        const float v = (col < 4) ? acc1[mt][r] : acc2[mt][r];
                        gparts[(q * 64 + mt * 16 + rbase + r) * 17 + col] = v;
                    }
            }
        }
        __syncthreads();
        const float s1 = gsum(gparts, eb, eu);
        if (t > 0) ustate += gsum(gparts, eb, 4 + eu) + cbv;
        const float rv = fmaxf(s1 + ustate + fcb, 0.f);
        relub[t * 65536 + blk * 256 + tid] = (unsigned short)f2bf(rv);
    };

    // ---- encoder: 64 steps x {L0, barrier, L1} (post-L1 barrier elided) ----
    for (int t = 0; t < 64; t++) {
        do_l0(h0buf[(t + 1) & 1], h0buf[t & 1], nullptr, t);
        gbar(bar, tgt++, grpId);
        do_l1(h0buf[t & 1], h1buf[(t + 1) & 1], h1buf[t & 1]);
    }
    // ---- decoder: 32 steps x {L0, b, L1, b, FC, b} ----
    for (int t = 0; t < 32; t++) {
        const unsigned short* rp = (t > 0) ? (relub + (t - 1) * 65536) : nullptr;
        do_l0(h0buf[(t + 1) & 1], h0buf[t & 1], rp, (t == 0) ? 63 : -1);
        gbar(bar, tgt++, grpId);
        do_l1(h0buf[t & 1], h1buf[(t + 1) & 1], h1buf[t & 1]);
        gbar(bar, tgt++, grpId);
        do_fc(t, h1buf[t & 1], rp);
        gbar(bar, tgt++, grpId);
    }

    // ---- final: pred[t] = relu[t] @ W2^T + b2 -> out[b][t][m] ----
    {
        const int pj = tid >> 5;   // 8 (t,b) pairs per block
        const int m = tid & 31;
        if (m < 20) {
            const int pidx = blk * 8 + pj;
            const int tt = pidx >> 6, bb = pidx & 63;
            const unsigned short* rr = relub + tt * 65536;
            const float* w = W2 + m * 1024;
            float acc = 0.f;
            for (int k2 = 0; k2 < 1024; k2 += 4) {
                short4_ r4 = *(const short4_*)(rr + (k2 >> 2) * 256 + bb * 4);
#pragma unroll
                for (int j = 0; j < 4; j++)
                    acc += bf2f((unsigned short)r4[j]) * w[k2 + j];
            }
            out[bb * 640 + tt * 20 + m] = acc + b2[m];
        }
    }
}

extern "C" void kernel_launch(void* const* d_in, const int* in_sizes, int n_in,
                              void* d_out, int out_size, void* d_ws, size_t ws_size,
                              hipStream_t stream) {
    (void)in_sizes; (void)n_in; (void)out_size; (void)ws_size;
    const float* x     = (const float*)d_in[0];
    const float* lastp = (const float*)d_in[1];
    const float* Wih0  = (const float*)d_in[2];
    const float* Whh0  = (const float*)d_in[3];
    const float* bih0  = (const float*)d_in[4];
    const float* bhh0  = (const float*)d_in[5];
    const float* Wih1  = (const float*)d_in[6];
    const float* Whh1  = (const float*)d_in[7];
    const float* bih1  = (const float*)d_in[8];
    const float* bhh1  = (const float*)d_in[9];
    const float* W1    = (const float*)d_in[10];
    const float* b1    = (const float*)d_in[11];
    const float* W2    = (const float*)d_in[12];
    const float* b2    = (const float*)d_in[13];
    float* out = (float*)d_out;
    unsigned char* ws = (unsigned char*)d_ws;

    void* args[] = {&x, &lastp, &Wih0, &Whh0, &bih0, &bhh0, &Wih1, &Whh1,
                    &bih1, &bhh1, &W1, &b1, &W2, &b2, &out, &ws};
    hipError_t err = hipLaunchCooperativeKernel((const void*)lstm_core,
                                                dim3(256), dim3(256), args, 0, stream);
    if (err != hipSuccess) {
        hipLaunchKernelGGL(lstm_core, dim3(256), dim3(256), 0, stream,
                           x, lastp, Wih0, Whh0, bih0, bhh0, Wih1, Whh1,
                           bih1, bhh1, W1, b1, W2, b2, out, ws);
    }
}

// Round 3
// 2468.717 us; speedup vs baseline: 2.2693x; 1.6347x over previous
//
// Persistent cooperative LSTM kernel for MI355X (gfx950) — round 3.
//  - 256 blocks x 256 threads, 1 block/CU. Block b owns hidden units 4b..4b+3
//    of BOTH layers. Weights live in VGPRs as bf16 MFMA B-fragments.
//  - R3 change vs R2 (which was fence-bound: dur tracked barrier count exactly,
//    24.4us/barrier = agent-fence L2 maintenance from 32 CUs/XCD x2/barrier):
//    NO __threadfence anywhere. h/relu traffic uses per-access coherence:
//      stores: global_store_dwordx2 sc0 sc1 (write-through to MALL)
//      loads:  global_load_dwordx4 sc0 sc1 (bypass L1/local L2, read MALL)
//    Barrier release = s_waitcnt vmcnt(0) in all threads before syncthreads
//    (sc-store commit point), acquire = loads are coherent by construction.
//  - h layout row-major h[b][1024] bf16; A-frag = one 16B coherent load;
//    stores LDS-staged to 64 x 8B per block.
#include <hip/hip_runtime.h>

typedef __attribute__((ext_vector_type(8))) short short8;
typedef __attribute__((ext_vector_type(4))) int int4_;
typedef __attribute__((ext_vector_type(4))) float float4_;

#define AGENT __HIP_MEMORY_SCOPE_AGENT

__device__ __forceinline__ unsigned short f2bf(float f) {
    unsigned u = __builtin_bit_cast(unsigned, f);
    u = (u + 0x7FFFu + ((u >> 16) & 1u)) >> 16;
    return (unsigned short)u;
}
__device__ __forceinline__ float bf2f(unsigned short h) {
    unsigned u = ((unsigned)h) << 16;
    return __builtin_bit_cast(float, u);
}
__device__ __forceinline__ float sigm(float x) { return 1.0f / (1.0f + __expf(-x)); }
__device__ __forceinline__ float tanhf_(float x) {
    x = fminf(fmaxf(x, -15.0f), 15.0f);
    float e = __expf(2.0f * x);
    return (e - 1.0f) / (e + 1.0f);
}

// coherent 8B store (write-through to coherence point)
__device__ __forceinline__ void st8_coh(unsigned short* p, unsigned long long v) {
    asm volatile("global_store_dwordx2 %0, %1, off sc0 sc1" :: "v"(p), "v"(v) : "memory");
}

// ---- grid barrier: NO fences. Release = vmcnt drain (sc-stores commit at
// coherence point); acquire = consumers use coherent loads. ----
__device__ __forceinline__ void gbar(unsigned* bar, unsigned target, int grpId) {
    asm volatile("s_waitcnt vmcnt(0)" ::: "memory");
    __syncthreads();
    if (threadIdx.x == 0) {
        unsigned old = __hip_atomic_fetch_add(bar + 256 + grpId * 16, 1u, __ATOMIC_RELAXED, AGENT);
        if ((old & 15u) == 15u) {
            unsigned old2 = __hip_atomic_fetch_add(bar + 512, 1u, __ATOMIC_RELAXED, AGENT);
            if ((old2 & 15u) == 15u) {
#pragma unroll
                for (int g = 0; g < 16; g++)
                    __hip_atomic_store(bar + g * 16, target, __ATOMIC_RELAXED, AGENT);
            }
        }
        while (__hip_atomic_load(bar + grpId * 16, __ATOMIC_RELAXED, AGENT) < target)
            __builtin_amdgcn_s_sleep(2);
    }
    __syncthreads();
}

__device__ __forceinline__ void zero4(float4_ (&a)[4]) {
    float4_ z;
    z[0] = 0.f; z[1] = 0.f; z[2] = 0.f; z[3] = 0.f;
#pragma unroll
    for (int i = 0; i < 4; i++) a[i] = z;
}

#define LD_COH(dst, base, OFF) \
    asm volatile("global_load_dwordx4 %0, %1, off offset:" #OFF " sc0 sc1" \
                 : "=v"(dst) : "v"(base))

// A row-major [64][1024] bf16. A-frag: m = lane&15 (+16*mt), k = quad*8+j.
// B[k][n]: n = lane&15, k = quad*8+j.  C[m][n]: n = lane&15, m = quad*4+reg.
// Loads are coherent (sc0 sc1); 16 in flight, explicit vmcnt drain with the
// fragments as +v operands so MFMAs can't be scheduled above the wait.
__device__ __forceinline__ void mm_pass(const unsigned short* __restrict__ A,
                                        int q, int lane,
                                        const short8 (&bf)[8], float4_ (&acc)[4]) {
    const int r0 = lane & 15;
    const int kq = (q << 8) + ((lane >> 4) << 3);
#pragma unroll
    for (int h = 0; h < 2; h++) {
        int4_ f[2][8];
#pragma unroll
        for (int mt2 = 0; mt2 < 2; mt2++) {
            const unsigned short* Ar = A + ((h * 2 + mt2) * 16 + r0) * 1024 + kq;
            LD_COH(f[mt2][0], Ar, 0);
            LD_COH(f[mt2][1], Ar, 64);
            LD_COH(f[mt2][2], Ar, 128);
            LD_COH(f[mt2][3], Ar, 192);
            LD_COH(f[mt2][4], Ar, 256);
            LD_COH(f[mt2][5], Ar, 320);
            LD_COH(f[mt2][6], Ar, 384);
            LD_COH(f[mt2][7], Ar, 448);
        }
        asm volatile("s_waitcnt vmcnt(0)"
                     : "+v"(f[0][0]), "+v"(f[0][1]), "+v"(f[0][2]), "+v"(f[0][3]),
                       "+v"(f[0][4]), "+v"(f[0][5]), "+v"(f[0][6]), "+v"(f[0][7]),
                       "+v"(f[1][0]), "+v"(f[1][1]), "+v"(f[1][2]), "+v"(f[1][3]),
                       "+v"(f[1][4]), "+v"(f[1][5]), "+v"(f[1][6]), "+v"(f[1][7]));
#pragma unroll
        for (int mt2 = 0; mt2 < 2; mt2++)
#pragma unroll
            for (int s = 0; s < 8; s++)
                acc[h * 2 + mt2] = __builtin_amdgcn_mfma_f32_16x16x32_bf16(
                    __builtin_bit_cast(short8, f[mt2][s]), bf[s], acc[h * 2 + mt2], 0, 0, 0);
    }
}

__device__ __forceinline__ void write_parts(float* gp, int q, int lane, float4_ (&acc)[4]) {
    const int col = lane & 15;
    const int rbase = (lane >> 4) * 4;
#pragma unroll
    for (int mt = 0; mt < 4; mt++)
#pragma unroll
        for (int r = 0; r < 4; r++)
            gp[(q * 64 + mt * 16 + rbase + r) * 17 + col] = acc[mt][r];
}

__device__ __forceinline__ float gsum(const float* gp, int b, int c) {
    return gp[(0 * 64 + b) * 17 + c] + gp[(1 * 64 + b) * 17 + c] +
           gp[(2 * 64 + b) * 17 + c] + gp[(3 * 64 + b) * 17 + c];
}

__device__ __forceinline__ short8 packrow(const float* __restrict__ p) {
    short8 r;
#pragma unroll
    for (int j = 0; j < 8; j++) r[j] = (short)f2bf(p[j]);
    return r;
}

__global__ void __launch_bounds__(256, 1)
lstm_core(const float* __restrict__ x, const float* __restrict__ lastp,
          const float* __restrict__ Wih0, const float* __restrict__ Whh0,
          const float* __restrict__ bih0, const float* __restrict__ bhh0,
          const float* __restrict__ Wih1, const float* __restrict__ Whh1,
          const float* __restrict__ bih1, const float* __restrict__ bhh1,
          const float* __restrict__ W1, const float* __restrict__ b1,
          const float* __restrict__ W2, const float* __restrict__ b2,
          float* __restrict__ out, unsigned char* __restrict__ wsb)
{
    const int tid = threadIdx.x;
    const int blk = blockIdx.x;
    const int lane = tid & 63;
    const int q = tid >> 6;          // wave id = K quarter
    const int grpId = blk & 15;
    const int eb = tid >> 2;         // epilogue: batch row
    const int eu = tid & 3;          // epilogue: unit-within-block
    const int D_ = blk * 4 + eu;     // global hidden unit / fc dim

    unsigned* bar = (unsigned*)wsb;
    // row-major bf16 buffers: h[b][1024]
    unsigned short* h0buf[2] = {(unsigned short*)(wsb + 8192),
                                (unsigned short*)(wsb + 8192 + 131072)};
    unsigned short* h1buf[2] = {(unsigned short*)(wsb + 270336),
                                (unsigned short*)(wsb + 270336 + 131072)};
    unsigned short* relub = (unsigned short*)(wsb + 532480); // 32 x [64][1024]

    __shared__ float gparts[4 * 64 * 17];
    __shared__ float xlds[64 * 21];
    __shared__ float wih0l[16 * 20];
    __shared__ unsigned long long hstage_u64[64];
    unsigned short* hstage = (unsigned short*)hstage_u64;

    // ---- barrier area init (block 0) ----
    if (blk == 0 && tid == 0) {
        for (int g = 0; g < 16; g++) {
            __hip_atomic_store(bar + g * 16, 0u, __ATOMIC_RELAXED, AGENT);
            __hip_atomic_store(bar + 256 + g * 16, 0u, __ATOMIC_RELAXED, AGENT);
        }
        __hip_atomic_store(bar + 512, 0u, __ATOMIC_RELAXED, AGENT);
        __hip_atomic_store(bar + 544, 0x1357BDFu, __ATOMIC_RELEASE, AGENT);
    }

    // ---- per-lane B-fragment preload (bf16, RNE) ----
    const int n_ = lane & 15;
    const int gq_ = n_ >> 2, uu_ = n_ & 3;
    const int growL = gq_ * 1024 + blk * 4 + uu_;   // gate row for this col
    const int kq = (q << 8) + ((lane >> 4) << 3);

    short8 whh0f[8], wih1f[8], whh1f[8], wfusedf[8], wfcf[8];
#pragma unroll
    for (int s = 0; s < 8; s++) {
        const int k = kq + s * 32;
        whh0f[s] = packrow(Whh0 + growL * 1024 + k);
        wih1f[s] = packrow(Wih1 + growL * 1024 + k);
        whh1f[s] = packrow(Whh1 + growL * 1024 + k);
        { // Wfused[row][k] = sum_m Wih0[row][m] * W2[m][k]
            float a8[8] = {0.f, 0.f, 0.f, 0.f, 0.f, 0.f, 0.f, 0.f};
            for (int m = 0; m < 20; m++) {
                float wv = Wih0[growL * 20 + m];
                const float* w2p = W2 + m * 1024 + k;
#pragma unroll
                for (int j = 0; j < 8; j++) a8[j] += wv * w2p[j];
            }
            short8 r;
#pragma unroll
            for (int j = 0; j < 8; j++) r[j] = (short)f2bf(a8[j]);
            wfusedf[s] = r;
        }
        { // fc B: cols 0-3 = W1h rows, cols 4-7 = Wskip rows, 8-15 = 0
            short8 r;
            if (n_ < 4) {
                r = packrow(W1 + (blk * 4 + n_) * 1040 + k);
            } else if (n_ < 8) {
                const int D = blk * 4 + (n_ - 4);
                float a8[8] = {0.f, 0.f, 0.f, 0.f, 0.f, 0.f, 0.f, 0.f};
                for (int g2 = 0; g2 < 16; g2++) {
                    const int m = 5 * (g2 >> 2) + (g2 & 3);
                    float wv = W1[D * 1040 + 1024 + g2] * 0.01f;
                    const float* w2p = W2 + m * 1024 + k;
#pragma unroll
                    for (int j = 0; j < 8; j++) a8[j] += wv * w2p[j];
                }
#pragma unroll
                for (int j = 0; j < 8; j++) r[j] = (short)f2bf(a8[j]);
            } else {
#pragma unroll
                for (int j = 0; j < 8; j++) r[j] = 0;
            }
            wfcf[s] = r;
        }
    }

    // ---- per-thread constants (epilogue mapping: eb = tid>>2, eu = tid&3) ----
    float bias0g[4], bias1g[4], cgv[4];
#pragma unroll
    for (int g = 0; g < 4; g++) {
        const int row = g * 1024 + D_;
        bias0g[g] = bih0[row] + bhh0[row];
        bias1g[g] = bih1[row] + bhh1[row];
        float s = 0.f;
        for (int m = 0; m < 20; m++) s += Wih0[row * 20 + m] * b2[m];
        cgv[g] = s;
    }
    const float fcb = b1[D_];
    float cbv = 0.f, ustate = 0.f;
    for (int g2 = 0; g2 < 16; g2++) {
        const float w1v = W1[D_ * 1040 + 1024 + g2];
        cbv += b2[5 * (g2 >> 2) + (g2 & 3)] * w1v * 0.01f;
        ustate += lastp[eb * 16 + g2] * w1v;   // u(0) = lp0 @ W1lp^T
    }
    float c0v = 0.f, c1v = 0.f;

    if (tid < 16) { // Wih0 rows for x-path (fp32, exact)
        const int row = (tid >> 2) * 1024 + blk * 4 + (tid & 3);
        for (int m = 0; m < 20; m++) wih0l[tid * 20 + m] = Wih0[row * 20 + m];
    }
    // zero initial h state (parity 1 is "t = -1"); coherent stores
    if (tid < 64) {
        st8_coh(h0buf[1] + tid * 1024 + blk * 4, 0ull);
        st8_coh(h1buf[1] + tid * 1024 + blk * 4, 0ull);
    }

    if (tid == 0) {
        while (__hip_atomic_load(bar + 544, __ATOMIC_RELAXED, AGENT) != 0x1357BDFu)
            __builtin_amdgcn_s_sleep(2);
    }
    unsigned tgt = 1;
    gbar(bar, tgt++, grpId);

    // ---- phase lambdas ----
    auto stage_and_store = [&](unsigned short* dst, unsigned short val) {
        hstage[tid] = val;           // hstage[eb*4+eu] == hstage[tid]
        __syncthreads();
        if (tid < 64)
            st8_coh(dst + tid * 1024 + blk * 4, hstage_u64[tid]);
    };

    auto do_l0 = [&](const unsigned short* h0prev, unsigned short* h0dst,
                     const unsigned short* reluprev, int xt) {
        float4_ acc[4];
        zero4(acc);
        mm_pass(h0prev, q, lane, whh0f, acc);
        if (reluprev) mm_pass(reluprev, q, lane, wfusedf, acc);
        if (xt >= 0) {
            for (int i = tid; i < 1280; i += 256) {
                const int bb = i / 20, mm = i - bb * 20;
                xlds[bb * 21 + mm] = x[bb * 1280 + xt * 20 + mm];
            }
        }
        write_parts(gparts, q, lane, acc);
        __syncthreads();
        float gv[4];
#pragma unroll
        for (int g = 0; g < 4; g++) gv[g] = gsum(gparts, eb, g * 4 + eu) + bias0g[g];
        if (xt >= 0) {
#pragma unroll
            for (int g = 0; g < 4; g++) {
                float s = 0.f;
                const float* wr = &wih0l[(g * 4 + eu) * 20];
                const float* xr = &xlds[eb * 21];
                for (int m = 0; m < 20; m++) s += xr[m] * wr[m];
                gv[g] += s;
            }
        } else {
#pragma unroll
            for (int g = 0; g < 4; g++) gv[g] += cgv[g];
        }
        const float iv = sigm(gv[0]), fv = sigm(gv[1]);
        const float gt = tanhf_(gv[2]), ov = sigm(gv[3]);
        c0v = fv * c0v + iv * gt;
        stage_and_store(h0dst, f2bf(ov * tanhf_(c0v)));
    };

    auto do_l1 = [&](const unsigned short* h0cur, const unsigned short* h1prev,
                     unsigned short* h1dst) {
        float4_ acc[4];
        zero4(acc);
        mm_pass(h0cur, q, lane, wih1f, acc);
        mm_pass(h1prev, q, lane, whh1f, acc);
        write_parts(gparts, q, lane, acc);
        __syncthreads();
        float gv[4];
#pragma unroll
        for (int g = 0; g < 4; g++) gv[g] = gsum(gparts, eb, g * 4 + eu) + bias1g[g];
        const float iv = sigm(gv[0]), fv = sigm(gv[1]);
        const float gt = tanhf_(gv[2]), ov = sigm(gv[3]);
        c1v = fv * c1v + iv * gt;
        stage_and_store(h1dst, f2bf(ov * tanhf_(c1v)));
    };

    auto do_fc = [&](int t, const unsigned short* h1cur, const unsigned short* reluprev) {
        float4_ acc1[4], acc2[4];
        zero4(acc1);
        zero4(acc2);
        mm_pass(h1cur, q, lane, wfcf, acc1);              // cols 0-3 valid: W1h@h1
        if (reluprev) mm_pass(reluprev, q, lane, wfcf, acc2); // cols 4-7: Wskip@relu
        {
            const int col = lane & 15;
            const int rbase = (lane >> 4) * 4;
            if (col < 8) {
#pragma unroll
                for (int mt = 0; mt < 4; mt++)
#pragma unroll
                    for (int r = 0; r < 4; r++) {
                        const float v = (col < 4) ? acc1[mt][r] : acc2[mt][r];
                        gparts[(q * 64 + mt * 16 + rbase + r) * 17 + col] = v;
                    }
            }
        }
        __syncthreads();
        const float s1 = gsum(gparts, eb, eu);
        if (t > 0) ustate += gsum(gparts, eb, 4 + eu) + cbv;
        const float rv = fmaxf(s1 + ustate + fcb, 0.f);
        stage_and_store(relub + t * 65536, f2bf(rv));
    };

    // ---- encoder: 64 steps x {L0, barrier, L1} (post-L1 barrier elided) ----
    for (int t = 0; t < 64; t++) {
        do_l0(h0buf[(t + 1) & 1], h0buf[t & 1], nullptr, t);
        gbar(bar, tgt++, grpId);
        do_l1(h0buf[t & 1], h1buf[(t + 1) & 1], h1buf[t & 1]);
    }
    // ---- decoder: 32 steps x {L0, b, L1, b, FC, b} ----
    for (int t = 0; t < 32; t++) {
        const unsigned short* rp = (t > 0) ? (relub + (t - 1) * 65536) : nullptr;
        do_l0(h0buf[(t + 1) & 1], h0buf[t & 1], rp, (t == 0) ? 63 : -1);
        gbar(bar, tgt++, grpId);
        do_l1(h0buf[t & 1], h1buf[(t + 1) & 1], h1buf[t & 1]);
        gbar(bar, tgt++, grpId);
        do_fc(t, h1buf[t & 1], rp);
        gbar(bar, tgt++, grpId);
    }

    // ---- final: pred[t] = relu[t] @ W2^T + b2 -> out[b][t][m] ----
    {
        const int pj = tid >> 5;   // 8 (t,b) pairs per block
        const int m = tid & 31;
        if (m < 20) {
            const int pidx = blk * 8 + pj;
            const int tt = pidx >> 6, bb = pidx & 63;
            const unsigned short* rr = relub + tt * 65536 + bb * 1024;
            const float* w = W2 + m * 1024;
            float acc = 0.f;
            for (int k2 = 0; k2 < 1024; k2 += 8) {
                short8 r8 = *(const short8*)(rr + k2);
#pragma unroll
                for (int j = 0; j < 8; j++)
                    acc += bf2f((unsigned short)r8[j]) * w[k2 + j];
            }
            out[bb * 640 + tt * 20 + m] = acc + b2[m];
        }
    }
}

extern "C" void kernel_launch(void* const* d_in, const int* in_sizes, int n_in,
                              void* d_out, int out_size, void* d_ws, size_t ws_size,
                              hipStream_t stream) {
    (void)in_sizes; (void)n_in; (void)out_size; (void)ws_size;
    const float* x     = (const float*)d_in[0];
    const float* lastp = (const float*)d_in[1];
    const float* Wih0  = (const float*)d_in[2];
    const float* Whh0  = (const float*)d_in[3];
    const float* bih0  = (const float*)d_in[4];
    const float* bhh0  = (const float*)d_in[5];
    const float* Wih1  = (const float*)d_in[6];
    const float* Whh1  = (const float*)d_in[7];
    const float* bih1  = (const float*)d_in[8];
    const float* bhh1  = (const float*)d_in[9];
    const float* W1    = (const float*)d_in[10];
    const float* b1    = (const float*)d_in[11];
    const float* W2    = (const float*)d_in[12];
    const float* b2    = (const float*)d_in[13];
    float* out = (float*)d_out;
    unsigned char* ws = (unsigned char*)d_ws;

    void* args[] = {&x, &lastp, &Wih0, &Whh0, &bih0, &bhh0, &Wih1, &Whh1,
                    &bih1, &bhh1, &W1, &b1, &W2, &b2, &out, &ws};
    hipError_t err = hipLaunchCooperativeKernel((const void*)lstm_core,
                                                dim3(256), dim3(256), args, 0, stream);
    if (err != hipSuccess) {
        hipLaunchKernelGGL(lstm_core, dim3(256), dim3(256), 0, stream,
                           x, lastp, Wih0, Whh0, bih0, bhh0, Wih1, Whh1,
                           bih1, bhh1, W1, b1, W2, b2, out, ws);
    }
}